// Round 12
// baseline (35.320 us; speedup 1.0000x reference)
//
#include <hip/hip_runtime.h>
#include <hip/hip_bf16.h>

#define B_SZ   256
#define N_IN   128
#define F_IN   64
#define G_SZ   128
#define F_OUT  64
#define S_SZ   16
#define K_TOT  1024   // S_SZ * F_IN
#define NSTEP  16     // K-steps of 64 (one gathered row each)

#define THREADS 256   // 4 waves/block; 512 blocks
// wave task: (g, mt, wr, wc) -> 32 m-rows x 32 o-cols output tile

typedef __attribute__((ext_vector_type(8))) short short8;  // 8 bf16
typedef __attribute__((ext_vector_type(4))) float f32x4;
typedef unsigned short u16;
typedef unsigned int   u32;

#define XN   (B_SZ * N_IN * F_IN)     // 2,097,152
#define WN   (G_SZ * F_OUT * K_TOT)   // 8,388,608
#define XN8  (XN / 8)
#define TOT8 ((XN + WN) / 8)          // 1,310,720

static __device__ __forceinline__ u32 packbf2(float a, float b) {
    // low 16 = a, high 16 = b (RNE); compiler emits v_cvt_pk_bf16_f32
    __hip_bfloat162 h = __float22bfloat162_rn(make_float2(a, b));
    union { __hip_bfloat162 h; u32 u; } c; c.h = h;
    return c.u;
}

// ---------------- pass 1: fp32 -> bf16 in FRAGMENT-MAJOR layouts ----------------
// xfr element index: ((bh*128 + n)*2 + ks)*64 + (kh*16 + bl)) * 8 + j
//   where b = bh*16+bl, k = ks*32 + kh*8 + j   (b in [0,256), n in [0,128), k in [0,64))
//   => the A-frag for (bh, n, ks) is ONE contiguous 1 KB line, lane = kh*16+bl.
// wfr element index: ((((g*16 + t)*2 + ks)*4 + ob)*64 + (kh*16 + ol)) * 8 + j
//   where o = ob*16+ol, k = t*64 + ks*32 + kh*8 + j
//   => the B-frag for (g, t, ks, ob) is ONE contiguous 1 KB line, lane = kh*16+ol.
// Both match the MFMA 16x16x32 operand layout: lane holds row (lane&15),
// k = (lane>>4)*8 + j within the 32-k window.
__global__ __launch_bounds__(256)
void convert_kernel(const float* __restrict__ x, const float* __restrict__ W,
                    u16* __restrict__ xfr, u16* __restrict__ wfr) {
    const int i = blockIdx.x * 256 + threadIdx.x;   // one 8-elem chunk (32B read)
    float4 v0, v1;
    u16* dst;
    int a16;                                        // 16B-chunk index in dest
    if (i < XN8) {
        v0 = reinterpret_cast<const float4*>(x)[i * 2];
        v1 = reinterpret_cast<const float4*>(x)[i * 2 + 1];
        const int b = i >> 10, n = (i >> 3) & 127, kc = i & 7;  // k = kc*8
        const int ks = kc >> 2, kh = kc & 3;
        a16 = (((b >> 4) * 128 + n) * 2 + ks) * 64 + (kh * 16 + (b & 15));
        dst = xfr;
    } else {
        const int iw = i - XN8;
        v0 = reinterpret_cast<const float4*>(W)[iw * 2];
        v1 = reinterpret_cast<const float4*>(W)[iw * 2 + 1];
        const int g = iw >> 13, o = (iw >> 7) & 63, kc = iw & 127;  // k = kc*8
        const int t = kc >> 3, ks = (kc >> 2) & 1, kh = kc & 3;
        a16 = (((g * 16 + t) * 2 + ks) * 4 + (o >> 4)) * 64 + (kh * 16 + (o & 15));
        dst = wfr;
    }
    uint4 p;
    p.x = packbf2(v0.x, v0.y); p.y = packbf2(v0.z, v0.w);
    p.z = packbf2(v1.x, v1.y); p.w = packbf2(v1.z, v1.w);
    *reinterpret_cast<uint4*>(dst + (size_t)a16 * 8) = p;
}

// ---------------- pass 2: LDS-free, barrier-free, asm-free grouped GEMM ----------------
// Every A/B fragment is a single wave-contiguous 1 KB global load (16B/lane)
// consumed directly by MFMA. ALL synchronization is register dependencies,
// which the compiler tracks with exact counted vmcnt waits. No manual ledger.
__global__ __launch_bounds__(THREADS)
void sparse_linear_kernel(const u16*   __restrict__ xfr,
                          const u16*   __restrict__ wfr,
                          const int*   __restrict__ idx,
                          const float* __restrict__ bias,
                          float*       __restrict__ out)
{
    const int blk  = blockIdx.x;        // 0..511
    const int g    = blk & 127;         // blk, blk+128,.. share W[g]: same XCD (128%8==0)
    const int half = blk >> 7;          // 0..3
    const int mt   = half >> 1;         // 0..1: m-tile of 128 batches
    const int wrp  = half & 1;          // wr pair

    const int tid  = threadIdx.x;
    const int w    = tid >> 6;          // 0..3
    const int lane = tid & 63;
    const int wr   = wrp * 2 + (w >> 1);   // 0..3 (32 m-rows each)
    const int wc   = w & 1;                // 0..1 (32 o-cols each)
    const int lmod = lane & 15;
    const int ldiv = lane >> 4;

    int rows[NSTEP];
    #pragma unroll
    for (int s = 0; s < NSTEP; ++s) rows[s] = idx[g * S_SZ + s];

    // A frag base pointers (add rows[t]*1024 elems per step):
    //   elem = (((bh*128 + n)*2 + ks)*64 + lane)*8, bh = mt*8 + wr*2 + mi
    const u16* aP[2][2];
    #pragma unroll
    for (int mi = 0; mi < 2; ++mi)
        #pragma unroll
        for (int ks = 0; ks < 2; ++ks) {
            const int bh = mt * 8 + wr * 2 + mi;
            aP[mi][ks] = xfr + ((size_t)((bh * 256 + ks) * 64 + lane)) * 8;
        }
    // B frag base pointers (add t*4096 elems per step):
    //   elem = ((((g*16+t)*2 + ks)*4 + ob)*64 + lane)*8, ob = wc*2 + ni
    const u16* wP[2][2];
    #pragma unroll
    for (int ni = 0; ni < 2; ++ni)
        #pragma unroll
        for (int ks = 0; ks < 2; ++ks) {
            const int ob = wc * 2 + ni;
            wP[ni][ks] = wfr + ((size_t)(((g * 32 + ks) * 4 + ob) * 64 + lane)) * 8;
        }

    f32x4  acc[2][2] = {};
    short8 Af[3][2][2];                 // [set][mi][ks]
    short8 Bf[3][2][2];                 // [set][ni][ks]

    #define LOADT(t, s)                                                        \
        {                                                                      \
            const int ro = rows[t] * 1024;                                     \
            _Pragma("unroll")                                                  \
            for (int mi = 0; mi < 2; ++mi)                                     \
                _Pragma("unroll")                                              \
                for (int ks = 0; ks < 2; ++ks)                                 \
                    Af[s][mi][ks] = *reinterpret_cast<const short8*>(          \
                        aP[mi][ks] + ro);                                      \
            _Pragma("unroll")                                                  \
            for (int ni = 0; ni < 2; ++ni)                                     \
                _Pragma("unroll")                                              \
                for (int ks = 0; ks < 2; ++ks)                                 \
                    Bf[s][ni][ks] = *reinterpret_cast<const short8*>(          \
                        wP[ni][ks] + (t) * 4096);                              \
        }

    #define COMP(s)                                                            \
        {                                                                      \
            _Pragma("unroll")                                                  \
            for (int ks = 0; ks < 2; ++ks)                                     \
                _Pragma("unroll")                                              \
                for (int mi = 0; mi < 2; ++mi)                                 \
                    _Pragma("unroll")                                          \
                    for (int ni = 0; ni < 2; ++ni)                             \
                        acc[mi][ni] = __builtin_amdgcn_mfma_f32_16x16x32_bf16( \
                            Af[s][mi][ks], Bf[s][ni][ks], acc[mi][ni], 0, 0, 0); \
        }

    // depth-3 register rotation, fully unrolled (static set indices).
    LOADT(0, 0);
    LOADT(1, 1);
    LOADT(2, 2);
    #pragma unroll
    for (int t = 0; t < NSTEP; ++t) {
        COMP(t % 3);                         // compiler emits counted vmcnt
        if (t + 3 < NSTEP) LOADT(t + 3, t % 3);
    }

    // ---- epilogue: C frag col = lane&15 (o), row = (lane>>4)*4 + r (m) ----
    const int rowbase = mt * 128 + wr * 32 + (ldiv << 2);
    #pragma unroll
    for (int ni = 0; ni < 2; ++ni) {
        const int o  = wc * 32 + ni * 16 + lmod;
        const float bv = bias[g * F_OUT + o];
        #pragma unroll
        for (int mi = 0; mi < 2; ++mi) {
            #pragma unroll
            for (int r = 0; r < 4; ++r) {
                const int brow = rowbase + mi * 16 + r;
                out[(size_t)brow * (G_SZ * F_OUT) + g * F_OUT + o] = acc[mi][ni][r] + bv;
            }
        }
    }
}

// ---- fallback (ws too small; not expected to run) ----
__global__ __launch_bounds__(256)
void naive_kernel(const float* __restrict__ x, const int* __restrict__ idx,
                  const float* __restrict__ W, const float* __restrict__ bias,
                  float* __restrict__ out) {
    const int i = blockIdx.x * 256 + threadIdx.x;   // (b, g, o)
    const int o = i & 63, gg = (i >> 6) & 127, b = i >> 13;
    float s = bias[gg * F_OUT + o];
    for (int t = 0; t < S_SZ; ++t) {
        const int r = idx[gg * S_SZ + t];
        #pragma unroll 8
        for (int f = 0; f < F_IN; ++f)
            s += x[(size_t)b * (N_IN * F_IN) + r * F_IN + f]
               * W[(size_t)gg * (F_OUT * K_TOT) + (size_t)o * K_TOT + t * F_IN + f];
    }
    out[i] = s;
}

extern "C" void kernel_launch(void* const* d_in, const int* in_sizes, int n_in,
                              void* d_out, int out_size, void* d_ws, size_t ws_size,
                              hipStream_t stream) {
    const float* x    = (const float*)d_in[0];
    const int*   idx  = (const int*)d_in[1];
    const float* W    = (const float*)d_in[2];
    const float* bias = (const float*)d_in[3];
    float*       out  = (float*)d_out;

    const size_t need = (size_t)(XN + WN) * sizeof(u16);   // 21 MB
    if (ws_size >= need) {
        u16* xfr = (u16*)d_ws;
        u16* wfr = xfr + XN;
        convert_kernel<<<dim3(TOT8 / 256), dim3(256), 0, stream>>>(x, W, xfr, wfr);
        sparse_linear_kernel<<<dim3(512), dim3(THREADS), 0, stream>>>(
            xfr, wfr, idx, bias, out);
    } else {
        naive_kernel<<<dim3((B_SZ * G_SZ * F_OUT) / 256), dim3(256), 0, stream>>>(
            x, idx, W, bias, out);
    }
}